// Round 4
// baseline (425.470 us; speedup 1.0000x reference)
//
#include <hip/hip_runtime.h>
#include <hip/hip_bf16.h>

#define H 64
#define OUTD 20
#define NGRAPH 8
#define NBK 256     // max buckets, 512 nodes each (covers N<=131072)
#define CAPB 8192   // ebuf slots per bucket (mean ~6.3K, 24-sigma margin; checked)
#define MAXDEG 63   // per-node edge cap (Poisson(16) max ~45)

typedef __attribute__((ext_vector_type(8))) short bf16x8;
typedef __attribute__((ext_vector_type(4))) float f32x4;
typedef __attribute__((ext_vector_type(8))) unsigned short u16x8;

// h layout: 2 FEATURE-HALVES of [N][32] bf16 -> 64B per node per half.
// r3: full-line gathers (4 lanes/edge read one 64B node entry) cut agg
// 74.6->46.3us; FETCH 96MB (6.4MB/XCD half > 4MB L2 -> ~44% L3 refills,
// acceptable). r4: softmax fused INTO agg (col holds plain src; s gathers
// are L2-hot 400KB) -> edge_weights dispatches + bucketD's latency-starved
// ew tail deleted; weights stay f32 (no 15-bit rounding).

__device__ __forceinline__ float ldp(const void* p, int i, bool f32) {
    return f32 ? ((const float*)p)[i]
               : __bfloat162float(((const __hip_bfloat16*)p)[i]);
}

__device__ __forceinline__ float bfu(unsigned short u) {
    union { unsigned int i; float f; } c; c.i = ((unsigned)u) << 16; return c.f;
}
__device__ __forceinline__ unsigned short fbits(float f) {
    __hip_bfloat16 b = __float2bfloat16(f);
    return *reinterpret_cast<unsigned short*>(&b);
}

// ---------------- dtype detection (sampled) ----------------
__global__ void detect_dtype(const unsigned short* __restrict__ xb, int n_u16,
                             int* __restrict__ flag) {
    __shared__ int sh[256];
    int t = threadIdx.x;
    int m = min(n_u16, 4096);
    int bad = 0;
    for (int i = t; i < m; i += 256) {
        unsigned e = (xb[i] >> 7) & 0xFF;
        bad += (e >= 0x90) ? 1 : 0;
    }
    sh[t] = bad;
    __syncthreads();
    for (int off = 128; off; off >>= 1) {
        if (t < off) sh[t] += sh[t + off];
        __syncthreads();
    }
    if (t == 0) *flag = (sh[0] > (m >> 4)) ? 1 : 0;  // 1 => float32
}

// ---------------- CSR build: fixed-capacity reservation scatter ----------------
// r5-r8 (prev session): per-edge global atomics cost 50-110MB coherence
// traffic; LDS counting + block-granular reservation is the cheap
// structure. r4: EPC=8 (784 fill blocks, 3 waves/SIMD) — the 2-pass
// histogram was latency-starved at 196 blocks (r3: 49us).
__global__ void fillC_dense0(const int* __restrict__ src, const int* __restrict__ dst,
                             int* __restrict__ gcur, unsigned* __restrict__ ebuf,
                             int E, int n, int nC, int EPC, int nbk,
                             const void* __restrict__ x, const void* __restrict__ W,
                             const void* __restrict__ a_s, const void* __restrict__ a_d,
                             __hip_bfloat16* __restrict__ h, float* __restrict__ s,
                             float* __restrict__ d, const int* __restrict__ flagp) {
    if ((int)blockIdx.x < nC) {
        __shared__ unsigned lcnt[NBK];
        __shared__ int lbase[NBK];
        int t = threadIdx.x;
        for (int i = t; i < NBK; i += 256) lcnt[i] = 0;
        __syncthreads();
        int base = blockIdx.x * (256 * EPC) + t;
        for (int i = 0; i < EPC; ++i) {
            int e = base + i * 256;
            if (e < E) {
                int dn = dst[e];
                if ((unsigned)dn < (unsigned)n) atomicAdd(&lcnt[dn >> 9], 1u);
            }
        }
        __syncthreads();
        for (int i = t; i < nbk; i += 256) {
            unsigned c = lcnt[i];
            lbase[i] = c ? atomicAdd(&gcur[i], (int)c) : 0;
            lcnt[i] = 0;
        }
        __syncthreads();
        for (int i = 0; i < EPC; ++i) {
            int e = base + i * 256;
            if (e < E) {
                int dn = dst[e];
                if ((unsigned)dn < (unsigned)n) {
                    int b = dn >> 9;
                    unsigned pos = (unsigned)lbase[b] + atomicAdd(&lcnt[b], 1u);
                    if (pos < CAPB)
                        ebuf[(size_t)b * CAPB + pos] =
                            ((unsigned)src[e] << 9) | (unsigned)(dn & 511);
                }
            }
        }
        return;
    }
    // ---- dense0: h = x @ W0 (din=3), s/d logit dots; h written half-sliced ----
    const bool f32 = (*flagp != 0);
    int idx = ((int)blockIdx.x - nC) * 256 + threadIdx.x;
    int node = idx >> 6;
    int f = idx & 63;
    if (node >= n) return;
    float acc = 0.f;
    for (int k = 0; k < 3; ++k)
        acc += ldp(x, node * 3 + k, f32) * ldp(W, k * H + f, f32);
    ((short*)h)[((size_t)(f >> 5) * n + node) * 32 + (f & 31)] = (short)fbits(acc);
    float sv = acc * ldp(a_s, f, f32);
    float dv = acc * ldp(a_d, f, f32);
    for (int off = 32; off; off >>= 1) {
        sv += __shfl_xor(sv, off);
        dv += __shfl_xor(dv, off);
    }
    if (f == 0) { s[node] = sv; d[node] = dv; }
}

// D: one block per bucket (512 nodes). Compact CSR: exclusive scan of
// (deg+1) slots -> cntoff[node] = off | deg<<24; col holds plain src.
// The +1 slot per node keeps the scan layout (self loop synthesized by
// the aggregate, never stored).
__global__ __launch_bounds__(512) void bucketD(const unsigned* __restrict__ ebuf,
                                               const int* __restrict__ gcur,
                                               unsigned* __restrict__ cntoff,
                                               int* __restrict__ col,
                                               int* __restrict__ gtot, int n) {
    __shared__ unsigned lcnt[512];
    __shared__ int loff[512];
    __shared__ int sc[512];
    __shared__ int sdeg[512];
    __shared__ int sbase;
    int b = blockIdx.x, t = threadIdx.x;
    lcnt[t] = 0;
    __syncthreads();
    int end = min(gcur[b], CAPB);
    const unsigned* reg = ebuf + (size_t)b * CAPB;
    for (int i = t; i < end; i += 512) atomicAdd(&lcnt[reg[i] & 511u], 1u);
    __syncthreads();
    int node = (b << 9) + t;
    int degc = (node < n) ? (int)min(lcnt[t], (unsigned)MAXDEG) : -1;
    int slots = degc + 1;           // 0 for out-of-range nodes
    sc[t] = slots;
    __syncthreads();
    for (int ofs = 1; ofs < 512; ofs <<= 1) {   // Hillis-Steele inclusive scan
        int v = (t >= ofs) ? sc[t - ofs] : 0;
        __syncthreads();
        sc[t] += v;
        __syncthreads();
    }
    if (t == 511) sbase = atomicAdd(gtot, sc[511]);
    __syncthreads();
    int myoff = sbase + sc[t] - slots;          // exclusive
    int dg = (degc > 0) ? degc : 0;
    loff[t] = myoff;
    sdeg[t] = dg;
    if (node < n) cntoff[node] = (unsigned)myoff | ((unsigned)dg << 24);
    lcnt[t] = 0;
    __syncthreads();
    for (int i = t; i < end; i += 512) {
        unsigned e = reg[i];
        int loc = (int)(e & 511u);
        unsigned pos = atomicAdd(&lcnt[loc], 1u);
        if ((int)pos < sdeg[loc])
            col[loff[loc] + pos] = (int)(e >> 9);
    }
}

// ---------------- GAT aggregation: fused softmax + full-line gather ----------
// blockIdx&7 -> (feature-half, node-quarter) pinned to one XCD (the gathered
// half = 6.4MB, L2+L3). 32 lanes/node: c=lane&3 sub-slice, q=lane>>2 edge
// slot (slots q+8k). Softmax inline: gather s[src] (L2-hot 400KB), leaky
// logits, q-lane reductions (shfl_xor 4/8/16; c lanes duplicate), exp with
// -INF masking (exp(-inf)=0), normalize once in epilogue. Slots 3..7
// (D>24, ~4% of waves) fully branch-guarded incl. their col/s/h loads.
#define ACC8(w, hv) { \
    a[0] += w * bfu(hv[0]); a[1] += w * bfu(hv[1]); \
    a[2] += w * bfu(hv[2]); a[3] += w * bfu(hv[3]); \
    a[4] += w * bfu(hv[4]); a[5] += w * bfu(hv[5]); \
    a[6] += w * bfu(hv[6]); a[7] += w * bfu(hv[7]); }

__global__ void gat_agg_sliced(const short* __restrict__ hs,
                               const float* __restrict__ s,
                               const float* __restrict__ d,
                               const unsigned* __restrict__ cntoff,
                               const int* __restrict__ col,
                               const void* __restrict__ bias,
                               short* __restrict__ outs, int n,
                               const int* __restrict__ flagp) {
    const bool f32 = (*flagp != 0);
    int shp = (int)blockIdx.x & 7;
    int fh = shp >> 2, nq = shp & 3;
    int qN = (n + 3) >> 2;
    int node = nq * qN + ((int)blockIdx.x >> 3) * 8 + ((int)threadIdx.x >> 5);
    int lim = min(n, (nq + 1) * qN);
    if (node >= lim) return;
    int l = threadIdx.x & 31;
    int c = l & 3, q = l >> 2;
    unsigned co = cntoff[node];
    int deg = (int)(co >> 24);
    int D = deg + 1;
    const int* cb = col + (co & 0xFFFFFFu);
    const u16x8* h8 = (const u16x8*)hs + (size_t)fh * n * 4 + c;
    float di = d[node];

    int e0 = q, e1 = q + 8, e2 = q + 16;
    // clamped unconditional loads (slots 0..deg allocated)
    int s0 = cb[min(e0, deg)];
    int s1 = cb[min(e1, deg)];
    int s2 = cb[min(e2, deg)];
    s0 = (e0 < deg) ? s0 : node;
    s1 = (e1 < deg) ? s1 : node;
    s2 = (e2 < deg) ? s2 : node;
    if ((unsigned)s0 >= (unsigned)n) s0 = 0;
    if ((unsigned)s1 >= (unsigned)n) s1 = 0;
    if ((unsigned)s2 >= (unsigned)n) s2 = 0;
    // logit gathers (4B, L2-hot) and h gathers (full 64B line) issue together
    float v0 = s[s0] + di, v1 = s[s1] + di, v2 = s[s2] + di;
    u16x8 hv0 = h8[(size_t)s0 * 4];
    u16x8 hv1 = h8[(size_t)s1 * 4];
    u16x8 hv2 = h8[(size_t)s2 * 4];
    v0 = v0 > 0.f ? v0 : 0.2f * v0;
    v1 = v1 > 0.f ? v1 : 0.2f * v1;
    v2 = v2 > 0.f ? v2 : 0.2f * v2;
    float sv0 = (e0 < D) ? v0 : -INFINITY;
    float sv1 = (e1 < D) ? v1 : -INFINITY;
    float sv2 = (e2 < D) ? v2 : -INFINITY;

    float sv3 = -INFINITY, sv4 = -INFINITY, sv5 = -INFINITY,
          sv6 = -INFINITY, sv7 = -INFINITY;
    u16x8 hv3 = {}, hv4 = {}, hv5 = {}, hv6 = {}, hv7 = {};
    bool big = (D > 24);
    if (big) {      // rare (P(deg>23) ~ 4%); execz-skipped when no lane needs it
        int e3 = q + 24, e4 = q + 32, e5 = q + 40, e6 = q + 48, e7 = q + 56;
        int s3 = cb[min(e3, deg)];
        int s4 = cb[min(e4, deg)];
        int s5 = cb[min(e5, deg)];
        int s6 = cb[min(e6, deg)];
        int s7 = cb[min(e7, deg)];
        s3 = (e3 < deg) ? s3 : node;
        s4 = (e4 < deg) ? s4 : node;
        s5 = (e5 < deg) ? s5 : node;
        s6 = (e6 < deg) ? s6 : node;
        s7 = (e7 < deg) ? s7 : node;
        if ((unsigned)s3 >= (unsigned)n) s3 = 0;
        if ((unsigned)s4 >= (unsigned)n) s4 = 0;
        if ((unsigned)s5 >= (unsigned)n) s5 = 0;
        if ((unsigned)s6 >= (unsigned)n) s6 = 0;
        if ((unsigned)s7 >= (unsigned)n) s7 = 0;
        float w3 = s[s3] + di, w4 = s[s4] + di, w5 = s[s5] + di,
              w6 = s[s6] + di, w7 = s[s7] + di;
        hv3 = h8[(size_t)s3 * 4];
        hv4 = h8[(size_t)s4 * 4];
        hv5 = h8[(size_t)s5 * 4];
        hv6 = h8[(size_t)s6 * 4];
        hv7 = h8[(size_t)s7 * 4];
        w3 = w3 > 0.f ? w3 : 0.2f * w3;
        w4 = w4 > 0.f ? w4 : 0.2f * w4;
        w5 = w5 > 0.f ? w5 : 0.2f * w5;
        w6 = w6 > 0.f ? w6 : 0.2f * w6;
        w7 = w7 > 0.f ? w7 : 0.2f * w7;
        sv3 = (e3 < D) ? w3 : -INFINITY;
        sv4 = (e4 < D) ? w4 : -INFINITY;
        sv5 = (e5 < D) ? w5 : -INFINITY;
        sv6 = (e6 < D) ? w6 : -INFINITY;
        sv7 = (e7 < D) ? w7 : -INFINITY;
    }

    // max over this lane's slots, then over q lanes (c lanes duplicate)
    float mx = fmaxf(fmaxf(fmaxf(sv0, sv1), fmaxf(sv2, sv3)),
                     fmaxf(fmaxf(sv4, sv5), fmaxf(sv6, sv7)));
    mx = fmaxf(mx, __shfl_xor(mx, 4));
    mx = fmaxf(mx, __shfl_xor(mx, 8));
    mx = fmaxf(mx, __shfl_xor(mx, 16));

    float w0 = __expf(sv0 - mx);    // exp(-inf - m) = 0: masking is free
    float w1 = __expf(sv1 - mx);
    float w2 = __expf(sv2 - mx);
    float wsum = w0 + w1 + w2;

    float a[8] = {0.f, 0.f, 0.f, 0.f, 0.f, 0.f, 0.f, 0.f};
    ACC8(w0, hv0);
    ACC8(w1, hv1);
    ACC8(w2, hv2);
    if (big) {
        float w3 = __expf(sv3 - mx);
        float w4 = __expf(sv4 - mx);
        float w5 = __expf(sv5 - mx);
        float w6 = __expf(sv6 - mx);
        float w7 = __expf(sv7 - mx);
        wsum += w3 + w4 + w5 + w6 + w7;
        ACC8(w3, hv3);
        ACC8(w4, hv4);
        ACC8(w5, hv5);
        ACC8(w6, hv6);
        ACC8(w7, hv7);
    }
    wsum += __shfl_xor(wsum, 4);
    wsum += __shfl_xor(wsum, 8);
    wsum += __shfl_xor(wsum, 16);
#pragma unroll
    for (int i = 0; i < 8; ++i) {
        a[i] += __shfl_xor(a[i], 4);
        a[i] += __shfl_xor(a[i], 8);
        a[i] += __shfl_xor(a[i], 16);
    }
    if (q == 0) {
        float inv = 1.f / fmaxf(wsum, 1e-20f);
        u16x8 ov;
        for (int i = 0; i < 8; ++i) {
            float o = a[i] * inv + ldp(bias, fh * 32 + c * 8 + i, f32);
            o = o > 0.f ? o : 0.01f * o;
            ov[i] = fbits(o);
        }
        ((u16x8*)outs)[((size_t)fh * n + node) * 4 + c] = ov;
    }
}

// ---------------- dense layers 1/2 via MFMA (half-sliced in/out) ----------------

__global__ __launch_bounds__(256) void denseN_mfma(
    const __hip_bfloat16* __restrict__ in,
    const void* __restrict__ W,
    const void* __restrict__ a_s, const void* __restrict__ a_d,
    __hip_bfloat16* __restrict__ h, float* __restrict__ s,
    float* __restrict__ d, int n, const int* __restrict__ flagp) {
    const bool f32 = (*flagp != 0);
    __shared__ short Wt[64 * 72];   // Wt[nf][k], padded
    int t = threadIdx.x;
    for (int i = t; i < 4096; i += 256) {
        int k = i >> 6, nf = i & 63;
        Wt[nf * 72 + k] = (short)fbits(ldp(W, i, f32));
    }
    __syncthreads();

    int wid = t >> 6, lane = t & 63;
    int quad = lane >> 4, n16 = lane & 15;
    int nodeBase = blockIdx.x * 64 + wid * 16;
    int mrow = nodeBase + n16;
    int mclamp = min(mrow, n - 1);
    const short* inp = (const short*)in;
    // half-sliced layout == MFMA A-fragment layout:
    // a0 = features [8q,8q+8) -> half 0; a1 = features [32+8q,..) -> half 1
    bf16x8 a0 = *(const bf16x8*)(inp + (size_t)mclamp * 32 + quad * 8);
    bf16x8 a1 = *(const bf16x8*)(inp + ((size_t)n + mclamp) * 32 + quad * 8);

    float as_v[4], ad_v[4];
    for (int nt = 0; nt < 4; ++nt) {
        as_v[nt] = ldp(a_s, nt * 16 + n16, f32);
        ad_v[nt] = ldp(a_d, nt * 16 + n16, f32);
    }

    float sv[4] = {0.f, 0.f, 0.f, 0.f}, dv[4] = {0.f, 0.f, 0.f, 0.f};
    f32x4 accs[4];
    for (int nt = 0; nt < 4; ++nt) {
        const short* wrow = Wt + (nt * 16 + n16) * 72;
        bf16x8 b0 = *(const bf16x8*)(wrow + quad * 8);
        bf16x8 b1 = *(const bf16x8*)(wrow + 32 + quad * 8);
        f32x4 cacc = {0.f, 0.f, 0.f, 0.f};
        cacc = __builtin_amdgcn_mfma_f32_16x16x32_bf16(a0, b0, cacc, 0, 0, 0);
        cacc = __builtin_amdgcn_mfma_f32_16x16x32_bf16(a1, b1, cacc, 0, 0, 0);
        accs[nt] = cacc;
        for (int r = 0; r < 4; ++r) {
            sv[r] += cacc[r] * as_v[nt];
            dv[r] += cacc[r] * ad_v[nt];
        }
    }

    short* hb = (short*)h;
    for (int r = 0; r < 4; ++r) {
        int node = nodeBase + quad * 4 + r;
        if (node < n) {
            for (int nt = 0; nt < 4; ++nt) {
                int f = nt * 16 + n16;
                hb[((size_t)(f >> 5) * n + node) * 32 + (f & 31)] = (short)fbits(accs[nt][r]);
            }
        }
    }
    for (int r = 0; r < 4; ++r) {
        for (int mask = 1; mask < 16; mask <<= 1) {
            sv[r] += __shfl_xor(sv[r], mask);
            dv[r] += __shfl_xor(dv[r], mask);
        }
    }
    if (n16 == 0) {
        for (int r = 0; r < 4; ++r) {
            int node = nodeBase + quad * 4 + r;
            if (node < n) { s[node] = sv[r]; d[node] = dv[r]; }
        }
    }
}

// ---------------- fused: MFMA node projection + vn pooling ----------------

__global__ __launch_bounds__(256) void proj_pool(
    const __hip_bfloat16* __restrict__ h,
    const void* __restrict__ W, const void* __restrict__ b,
    void* __restrict__ out, int n, const int* __restrict__ flagp,
    int projBlocks, const int* __restrict__ batch, float* __restrict__ vn) {
    const bool f32 = (*flagp != 0);
    if ((int)blockIdx.x < projBlocks) {
        __shared__ short Wt[32 * 72];   // Wt[o][k], rows 20..31 zero
        int t = threadIdx.x;
        for (int i = t; i < 32 * 64; i += 256) {
            int o = i >> 6, k = i & 63;
            Wt[o * 72 + k] = (o < OUTD) ? (short)fbits(ldp(W, k * OUTD + o, f32)) : 0;
        }
        __syncthreads();

        int wid = t >> 6, lane = t & 63;
        int quad = lane >> 4, n16 = lane & 15;
        int nodeBase = blockIdx.x * 64 + wid * 16;
        int mclamp = min(nodeBase + n16, n - 1);
        const short* hsrc = (const short*)h;
        bf16x8 a0 = *(const bf16x8*)(hsrc + (size_t)mclamp * 32 + quad * 8);
        bf16x8 a1 = *(const bf16x8*)(hsrc + ((size_t)n + mclamp) * 32 + quad * 8);

        f32x4 acc0 = {0.f, 0.f, 0.f, 0.f}, acc1 = {0.f, 0.f, 0.f, 0.f};
        {
            const short* wrow = Wt + n16 * 72;
            bf16x8 b0 = *(const bf16x8*)(wrow + quad * 8);
            bf16x8 b1 = *(const bf16x8*)(wrow + 32 + quad * 8);
            acc0 = __builtin_amdgcn_mfma_f32_16x16x32_bf16(a0, b0, acc0, 0, 0, 0);
            acc0 = __builtin_amdgcn_mfma_f32_16x16x32_bf16(a1, b1, acc0, 0, 0, 0);
        }
        {
            const short* wrow = Wt + (16 + n16) * 72;
            bf16x8 b0 = *(const bf16x8*)(wrow + quad * 8);
            bf16x8 b1 = *(const bf16x8*)(wrow + 32 + quad * 8);
            acc1 = __builtin_amdgcn_mfma_f32_16x16x32_bf16(a0, b0, acc1, 0, 0, 0);
            acc1 = __builtin_amdgcn_mfma_f32_16x16x32_bf16(a1, b1, acc1, 0, 0, 0);
        }
        float bv0 = ldp(b, n16, f32);
        float bv1 = (n16 < OUTD - 16) ? ldp(b, 16 + n16, f32) : 0.f;
        for (int r = 0; r < 4; ++r) {
            int node = nodeBase + quad * 4 + r;
            if (node >= n) break;
            float o0 = acc0[r] + bv0;
            if (f32) ((float*)out)[node * OUTD + n16] = o0;
            else     ((__hip_bfloat16*)out)[node * OUTD + n16] = __float2bfloat16(o0);
            if (n16 < OUTD - 16) {
                float o1 = acc1[r] + bv1;
                if (f32) ((float*)out)[node * OUTD + 16 + n16] = o1;
                else     ((__hip_bfloat16*)out)[node * OUTD + 16 + n16] = __float2bfloat16(o1);
            }
        }
        return;
    }
    // ---- pooling part (half-sliced h read) ----
    __shared__ float part[NGRAPH * H];
    int t = threadIdx.x;
    for (int i = t; i < NGRAPH * H; i += 256) part[i] = 0.f;
    __syncthreads();
    int pb = (int)blockIdx.x - projBlocks;
    int npb = gridDim.x - projBlocks;
    int wid = t >> 6, lane = t & 63;
    int gwave = pb * 4 + wid;
    int nwaves = npb * 4;
    int chunk = (n + nwaves - 1) / nwaves;
    int beg = gwave * chunk;
    int end = min(n, beg + chunk);
    if (beg < end) {
        const short* hb = (const short*)h + (size_t)(lane >> 5) * n * 32 + (lane & 31);
        float acc = 0.f;
        int cur = batch[beg];
        for (int i = beg; i < end; ++i) {
            int g = batch[i];
            if (g != cur) {
                if ((unsigned)cur < NGRAPH) atomicAdd(&part[cur * H + lane], acc);
                acc = 0.f;
                cur = g;
            }
            acc += bfu((unsigned short)hb[(size_t)i * 32]);
        }
        if ((unsigned)cur < NGRAPH) atomicAdd(&part[cur * H + lane], acc);
    }
    __syncthreads();
    for (int i = t; i < NGRAPH * H; i += 256) {
        float v = part[i];
        if (v != 0.f) atomicAdd(&vn[i], v);
    }
}

// ---------------- virtual-node MLP head (8x64, 4 layers) ----------------

__global__ void vn_mlp(const float* __restrict__ vn, const void* __restrict__ emb,
                       const void* __restrict__ w1, const void* __restrict__ b1,
                       const void* __restrict__ w2, const void* __restrict__ b2,
                       const void* __restrict__ w3, const void* __restrict__ b3,
                       const void* __restrict__ w4, const void* __restrict__ b4,
                       void* __restrict__ out, int out1_off, const int* __restrict__ flagp) {
    const bool f32 = (*flagp != 0);
    __shared__ float A[NGRAPH * H], B[NGRAPH * H];
    int t = threadIdx.x;          // 512 threads = 8 graphs x 64 feats
    int g = t >> 6, f = t & 63;
    A[t] = vn[t] + ldp(emb, f, f32);
    __syncthreads();
    float acc = ldp(b1, f, f32);
    for (int k = 0; k < H; ++k) acc += A[g * H + k] * ldp(w1, k * H + f, f32);
    B[t] = fmaxf(acc, 0.f);
    __syncthreads();
    acc = ldp(b2, f, f32);
    for (int k = 0; k < H; ++k) acc += B[g * H + k] * ldp(w2, k * H + f, f32);
    A[t] = fmaxf(acc, 0.f);
    __syncthreads();
    acc = ldp(b3, f, f32);
    for (int k = 0; k < H; ++k) acc += A[g * H + k] * ldp(w3, k * H + f, f32);
    B[t] = fmaxf(acc, 0.f);
    __syncthreads();
    if (f < OUTD) {
        acc = ldp(b4, f, f32);
        for (int k = 0; k < H; ++k) acc += B[g * H + k] * ldp(w4, k * OUTD + f, f32);
        acc = fmaxf(acc, 0.f);
        int idx = out1_off + g * OUTD + f;
        if (f32) ((float*)out)[idx] = acc;
        else     ((__hip_bfloat16*)out)[idx] = __float2bfloat16(acc);
    }
}

// ---------------- launcher ----------------

extern "C" void kernel_launch(void* const* d_in, const int* in_sizes, int n_in,
                              void* d_out, int out_size, void* d_ws, size_t ws_size,
                              hipStream_t stream) {
    const void* x   = d_in[0];
    const int* ei   = (const int*)d_in[1];
    const int* batch= (const int*)d_in[2];
    const void* W0  = d_in[3];
    const void* as0 = d_in[4];
    const void* ad0 = d_in[5];
    const void* b0  = d_in[6];
    const void* W1  = d_in[7];
    const void* as1 = d_in[8];
    const void* ad1 = d_in[9];
    const void* b1  = d_in[10];
    const void* W2  = d_in[11];
    const void* as2 = d_in[12];
    const void* ad2 = d_in[13];
    const void* b2  = d_in[14];
    const void* vne = d_in[15];
    const void* m1w1 = d_in[16];
    const void* m1b1 = d_in[17];
    const void* m1w2 = d_in[18];
    const void* m1b2 = d_in[19];
    const void* mfw1 = d_in[20];
    const void* mfb1 = d_in[21];
    const void* mfw2 = d_in[22];
    const void* mfb2 = d_in[23];
    const void* outw = d_in[24];
    const void* outb = d_in[25];

    const int N = in_sizes[2];
    const int E = in_sizes[1] / 2;
    const int* srcp = ei;
    const int* dstp = ei + E;

    // workspace carve (256B aligned) — total ~55 MB
    char* w = (char*)d_ws;
    auto alloc = [&](size_t bytes) -> void* {
        void* p = (void*)w;
        w += ((bytes + 255) / 256) * 256;
        return p;
    };
    int*   flag   = (int*)alloc(256);
    int*   gcur   = (int*)alloc((size_t)NBK * 4);
    int*   gtot   = (int*)alloc(256);
    unsigned* ebuf= (unsigned*)alloc((size_t)NBK * CAPB * 4);
    unsigned* cntoff = (unsigned*)alloc((size_t)N * 4);
    int*   col    = (int*)alloc(((size_t)E + N + 64) * 4);   // compact CSR
    __hip_bfloat16* featA = (__hip_bfloat16*)alloc((size_t)N * H * 2);
    __hip_bfloat16* featB = (__hip_bfloat16*)alloc((size_t)N * H * 2);
    __hip_bfloat16* hbuf  = (__hip_bfloat16*)alloc((size_t)N * H * 2);
    float* sArr   = (float*)alloc((size_t)N * 4);
    float* dArr   = (float*)alloc((size_t)N * 4);
    float* vn     = (float*)alloc((size_t)NGRAPH * H * 4);

    const int nbN64 = (N * H + 255) / 256;      // dense0 blocks (1 wave/node)
    const int nb64 = (N + 63) / 64;
    const int projBlocks = (N + 63) / 64;
    const int nbk = (N + 511) >> 9;
    const int qN = (N + 3) >> 2;
    const int aggBlocks = 8 * ((qN + 7) / 8);   // 8 nodes/block, 8 partitions
    int EPC = 8;                                // 784 fill blocks: latency-bound
    int nC = (E + 256 * EPC - 1) / (256 * EPC); // histogram needs the TLP (r3)
    while (nC > 1024) { EPC <<= 1; nC = (E + 256 * EPC - 1) / (256 * EPC); }

    // --- dtype probe (sampled) ---
    detect_dtype<<<1, 256, 0, stream>>>((const unsigned short*)x, in_sizes[0], flag);

    // --- CSR build: reservation scatter (+ dense0 fused), then compact place ---
    hipMemsetAsync(gcur, 0, (size_t)NBK * 4, stream);
    hipMemsetAsync(gtot, 0, 4, stream);
    hipMemsetAsync(vn, 0, (size_t)NGRAPH * H * 4, stream);
    fillC_dense0<<<nC + nbN64, 256, 0, stream>>>(
        srcp, dstp, gcur, ebuf, E, N, nC, EPC, nbk,
        x, W0, as0, ad0, hbuf, sArr, dArr, flag);
    bucketD<<<nbk, 512, 0, stream>>>(ebuf, gcur, cntoff, col, gtot, N);

    // --- GAT layers: dense (MFMA) -> aggregate (fused softmax) ---
    gat_agg_sliced<<<aggBlocks, 256, 0, stream>>>((const short*)hbuf, sArr, dArr,
                                                  cntoff, col, b0, (short*)featA, N, flag);
    denseN_mfma<<<nb64, 256, 0, stream>>>(featA, W1, as1, ad1, hbuf, sArr, dArr, N, flag);
    gat_agg_sliced<<<aggBlocks, 256, 0, stream>>>((const short*)hbuf, sArr, dArr,
                                                  cntoff, col, b1, (short*)featB, N, flag);
    denseN_mfma<<<nb64, 256, 0, stream>>>(featB, W2, as2, ad2, hbuf, sArr, dArr, N, flag);
    gat_agg_sliced<<<aggBlocks, 256, 0, stream>>>((const short*)hbuf, sArr, dArr,
                                                  cntoff, col, b2, (short*)featA, N, flag);

    // --- outputs: MFMA node projection + vn pooling fused ---
    proj_pool<<<projBlocks + 512, 256, 0, stream>>>(featA, outw, outb, d_out, N, flag,
                                                    projBlocks, batch, vn);
    vn_mlp<<<1, 512, 0, stream>>>(vn, vne, m1w1, m1b1, m1w2, m1b2, mfw1, mfb1, mfw2, mfb2,
                                  d_out, N * OUTD, flag);
}